// Round 8
// baseline (15436.113 us; speedup 1.0000x reference)
//
#include <hip/hip_runtime.h>
#include <hip/hip_fp16.h>

// B=64, T=512, D=96, H=256
constexpr int Tt = 512, Dd = 96, Hh = 256;
constexpr int NS = 16;   // ring depth (h0, h1)
typedef unsigned long long u64;

// workspace layout
constexpr size_t OFF_H0  = 0;                       // 2 chains x 16 slots x 64 x 256 u64 = 4MB
constexpr size_t OFF_H1  = (size_t)4 << 20;         // same, 4MB
constexpr size_t OFF_FLG = (size_t)8 << 20;         // 8 groups x 1024 ints = 32KB
constexpr size_t OFF_W16 = (size_t)9 << 20;         // packed fp16-pair weights (~3MB)
constexpr size_t oGW0 = 0;
constexpr size_t oGU0 = oGW0 + (size_t)48 * 768;
constexpr size_t oGW1 = oGU0 + (size_t)128 * 768;
constexpr size_t oGU1 = oGW1 + (size_t)128 * 768;
constexpr size_t oLW0 = oGU1 + (size_t)128 * 768;
constexpr size_t oLU0 = oLW0 + (size_t)48 * 1024;
constexpr size_t oLW1 = oLU0 + (size_t)128 * 1024;
constexpr size_t oLU1 = oLW1 + (size_t)128 * 1024;
constexpr size_t OFF_XP = (size_t)16 << 20;         // packed x fp16 pairs
constexpr size_t OFF_PG = (size_t)32 << 20;         // GRU P0 fp32 (96MB)
constexpr size_t SZ_PG  = (size_t)64 * 512 * 768 * 4;
constexpr size_t OFF_PL = OFF_PG + SZ_PG;           // LSTM P0 fp32 (128MB)
constexpr size_t SZ_PL  = (size_t)64 * 512 * 1024 * 4;
constexpr size_t WS_NEED = OFF_PL + SZ_PL;          // 256MB (harness proved available, R7)
constexpr int LDS_BYTES = 155648;                   // 152KB (max over roles)

__device__ __forceinline__ float sigf(float v) { return 1.0f / (1.0f + __expf(-v)); }
__device__ __forceinline__ u64 agld(const u64* p) {
    return __hip_atomic_load(p, __ATOMIC_RELAXED, __HIP_MEMORY_SCOPE_AGENT);
}
__device__ __forceinline__ int agldi(const int* p) {
    return __hip_atomic_load(p, __ATOMIC_ACQUIRE, __HIP_MEMORY_SCOPE_AGENT);
}
__device__ __forceinline__ void agst(u64* p, u64 v) {
    __hip_atomic_store(p, v, __ATOMIC_RELAXED, __HIP_MEMORY_SCOPE_AGENT);
}
__device__ __forceinline__ void xrel(int* p, int v) {
    __hip_atomic_exchange(p, v, __ATOMIC_RELEASE, __HIP_MEMORY_SCOPE_AGENT);
}
__device__ __forceinline__ float pollF(const u64* p, unsigned want) {
    u64 v = agld(p);
    while ((unsigned)v != want) v = agld(p);
    return __uint_as_float((unsigned)(v >> 32));
}

// fp16x2 dot into f32 accumulator (v_dot2_f32_f16)
__device__ __forceinline__ float dot2f(unsigned w, unsigned a, float acc) {
#if __has_builtin(__builtin_amdgcn_fdot2)
    typedef _Float16 h2v __attribute__((ext_vector_type(2)));
    h2v wh, ah;
    __builtin_memcpy(&wh, &w, 4);
    __builtin_memcpy(&ah, &a, 4);
    return __builtin_amdgcn_fdot2(wh, ah, acc, false);
#else
    const float2 wf = __half22float2(*(const __half2*)&w);
    const float2 af = __half22float2(*(const __half2*)&a);
    acc = fmaf(wf.x, af.x, acc);
    return fmaf(wf.y, af.y, acc);
#endif
}

// one 4-kp chunk of one weight column against a 4-row quad (16 dot2)
__device__ __forceinline__ void fmaC(const uint4 w, const uint4* __restrict__ A4,
                                     int kpb, float4& a) {
    const uint4 a0 = A4[kpb + 0], a1 = A4[kpb + 1], a2 = A4[kpb + 2], a3 = A4[kpb + 3];
    a.x = dot2f(w.x, a0.x, a.x); a.y = dot2f(w.x, a0.y, a.y);
    a.z = dot2f(w.x, a0.z, a.z); a.w = dot2f(w.x, a0.w, a.w);
    a.x = dot2f(w.y, a1.x, a.x); a.y = dot2f(w.y, a1.y, a.y);
    a.z = dot2f(w.y, a1.z, a.z); a.w = dot2f(w.y, a1.w, a.w);
    a.x = dot2f(w.z, a2.x, a.x); a.y = dot2f(w.z, a2.y, a.y);
    a.z = dot2f(w.z, a2.z, a.z); a.w = dot2f(w.z, a2.w, a.w);
    a.x = dot2f(w.w, a3.x, a.x); a.y = dot2f(w.w, a3.y, a.y);
    a.z = dot2f(w.w, a3.z, a.z); a.w = dot2f(w.w, a3.w, a.w);
}

// ---- gemmP helpers used only by the P0 prologue (R7-verbatim path) ----
template<int G>
__device__ __forceinline__ void load4h(uint4* wv, const uint4* __restrict__ M4,
                                       int ldm, int kpb) {
    const int base = (kpb >> 2) * ldm;
    #pragma unroll
    for (int g = 0; g < G; ++g)
        wv[g] = M4[base + g * 256];
}
template<int G>
__device__ __forceinline__ void fma4h(const uint4* wv, const uint4* __restrict__ A4,
                                      int kpb, float4* acc) {
    #pragma unroll
    for (int g = 0; g < G; ++g)
        fmaC(wv[g], A4, kpb, acc[g]);
}
template<int G>
__device__ __forceinline__ void gemmP(const uint4* __restrict__ M4, int ldm,
                                      const uint4* __restrict__ A4,
                                      int kp0, int kp1, float4* acc) {
    const int n4 = (kp1 - kp0) >> 2;
    uint4 wv0[G], wv1[G];
    if (n4 <= 0) return;
    load4h<G>(wv0, M4, ldm, kp0);
    int c2 = 0;
    for (; c2 + 2 <= n4; c2 += 2) {
        load4h<G>(wv1, M4, ldm, kp0 + (c2 + 1) * 4);
        fma4h<G>(wv0, A4, kp0 + c2 * 4, acc);
        if (c2 + 2 < n4) load4h<G>(wv0, M4, ldm, kp0 + (c2 + 2) * 4);
        fma4h<G>(wv1, A4, kp0 + (c2 + 1) * 4, acc);
    }
    if (c2 < n4) fma4h<G>(wv0, A4, kp0 + c2 * 4, acc);
}

// weight f32 -> paired fp16, chunk-tiled transposed layout (per launch)
__global__ void cvt_pair(const float* __restrict__ src, unsigned* __restrict__ dst,
                         int n, int ld) {
    const int i = blockIdx.x * 256 + threadIdx.x;
    if (i >= n) return;
    const int kp = i / ld, col = i - kp * ld;
    const __half2 h = __floats2half2_rn(src[(2 * kp) * ld + col],
                                        src[(2 * kp + 1) * ld + col]);
    dst[((size_t)((kp >> 2) * ld + col) << 2) + (kp & 3)] = *(const unsigned*)&h;
}

// pack x -> fp16 pairs over k
__global__ void pack_x(const float* __restrict__ x, unsigned* __restrict__ XP) {
    const int i = blockIdx.x * 256 + threadIdx.x;
    if (i >= 64 * Tt * 48) return;
    const int kp = i % 48;
    const int bt = i / 48;
    const __half2 h = __floats2half2_rn(x[(size_t)bt * Dd + 2 * kp],
                                        x[(size_t)bt * Dd + 2 * kp + 1]);
    XP[i] = *(const unsigned*)&h;
}

// Prologue: P0[chain][row][t][GA*256] = x(row,t) @ W0 + bias (R7-verified path).
__global__ void __launch_bounds__(1024, 4)
gemm_p0(const unsigned* __restrict__ XP, const float* __restrict__ gbi0,
        const float* __restrict__ lb0, char* __restrict__ wsb)
{
    const int tid = threadIdx.x;
    const int c   = tid & 255;
    const int grp = tid >> 8;
    const int bx  = blockIdx.x;
    const int tt = bx & 31, rg = (bx >> 5) & 15, chain = bx >> 9;
    const int rowbase = rg * 4;
    const int GA = chain ? 4 : 3;
    const int GAH = GA * Hh;
    const unsigned* W16 = (const unsigned*)(wsb + OFF_W16);
    const uint4* M4 = (const uint4*)(W16 + (chain ? oLW0 : oGW0)) + c;
    float* P0 = (float*)(wsb + (chain ? OFF_PL : OFF_PG));
    const float* bsrc = chain ? lb0 : gbi0;

    __shared__ __align__(16) unsigned sAh[512];
    __shared__ float sG[2 * 4096];
    const uint4* A4 = (const uint4*)sAh;
    const int kp0 = grp * 12, kp1 = kp0 + 12;
    const int npt = GA;
    float biasv[4]; int rs[4], remv[4];
    #pragma unroll
    for (int i = 0; i < 4; ++i) {
        if (i < npt) {
            const int e = tid + i * 1024;
            const int r = e / GAH, rem = e - r * GAH;
            biasv[i] = bsrc[rem]; rs[i] = r; remv[i] = rem;
        } else { biasv[i] = 0; rs[i] = 0; remv[i] = 0; }
    }
    for (int t = tt * 16; t < tt * 16 + 16; ++t) {
        if (tid < 192) {
            const int row = tid / 48, kp = tid - row * 48;
            sAh[kp * 4 + row] = XP[((size_t)(rowbase + row) * Tt + t) * 48 + kp];
        }
        __syncthreads();
        if (chain == 0) {
            float4 acc[3] = {{0,0,0,0},{0,0,0,0},{0,0,0,0}};
            gemmP<3>(M4, GAH, A4, kp0, kp1, acc);
            if (grp < 2) {
                #pragma unroll
                for (int g = 0; g < 3; ++g) {
                    sG[grp * 4096 + 0 + g * 256 + c]    = acc[g].x;
                    sG[grp * 4096 + 1024 + g * 256 + c] = acc[g].y;
                    sG[grp * 4096 + 2048 + g * 256 + c] = acc[g].z;
                    sG[grp * 4096 + 3072 + g * 256 + c] = acc[g].w;
                }
            }
            __syncthreads();
            if (grp >= 2) {
                const int b = (grp - 2) * 4096;
                #pragma unroll
                for (int g = 0; g < 3; ++g) {
                    sG[b + 0 + g * 256 + c]    += acc[g].x;
                    sG[b + 1024 + g * 256 + c] += acc[g].y;
                    sG[b + 2048 + g * 256 + c] += acc[g].z;
                    sG[b + 3072 + g * 256 + c] += acc[g].w;
                }
            }
        } else {
            float4 acc[4] = {{0,0,0,0},{0,0,0,0},{0,0,0,0},{0,0,0,0}};
            gemmP<4>(M4, GAH, A4, kp0, kp1, acc);
            if (grp < 2) {
                #pragma unroll
                for (int g = 0; g < 4; ++g) {
                    sG[grp * 4096 + 0 + g * 256 + c]    = acc[g].x;
                    sG[grp * 4096 + 1024 + g * 256 + c] = acc[g].y;
                    sG[grp * 4096 + 2048 + g * 256 + c] = acc[g].z;
                    sG[grp * 4096 + 3072 + g * 256 + c] = acc[g].w;
                }
            }
            __syncthreads();
            if (grp >= 2) {
                const int b = (grp - 2) * 4096;
                #pragma unroll
                for (int g = 0; g < 4; ++g) {
                    sG[b + 0 + g * 256 + c]    += acc[g].x;
                    sG[b + 1024 + g * 256 + c] += acc[g].y;
                    sG[b + 2048 + g * 256 + c] += acc[g].z;
                    sG[b + 3072 + g * 256 + c] += acc[g].w;
                }
            }
        }
        __syncthreads();
        for (int i = 0; i < npt; ++i) {
            const int idx = rs[i] * 1024 + remv[i];
            const float v = sG[idx] + sG[4096 + idx] + biasv[i];
            P0[((size_t)(rowbase + rs[i]) * Tt + t) * GAH + remv[i]] = v;
        }
        __syncthreads();
    }
}

// ===================== R8 main: LDS-resident-weight 2-stage pipeline =====================
// 96 blocks x 1024 threads.
//  bx <  32: kind 0 (r0): chain=bx>>4, rq=(bx>>2)&3, us=bx&3  (64-unit slice of U0)
//  bx >= 32: kind 1 (r1): i=bx-32: chain=i>>5, rq=(i>>3)&3, us=i&7 (32-unit slice, K=512 [W1;U1])
// flags (per chain,rq; fid*32 ints): 0..3 r0(us) "h0 consumed thru+1"; 8..15 r1(us) same;
//                                    16..23 r1(us) "h1 consumed thru+1".
__global__ void __launch_bounds__(1024, 1)
rnn_fused(const int* __restrict__ lengths, const float* __restrict__ gbr0,
          const float* __restrict__ gbi1, const float* __restrict__ gbr1,
          const float* __restrict__ lb1, const float* __restrict__ outW,
          const float* __restrict__ outb, float* __restrict__ out,
          char* __restrict__ wsb)
{
    extern __shared__ __align__(16) char smem[];
    const int tid = threadIdx.x;
    const int bx = blockIdx.x;
    int chain, rq, us, kind;
    if (bx < 32) { kind = 0; chain = bx >> 4; rq = (bx >> 2) & 3; us = bx & 3; }
    else { const int i = bx - 32; kind = 1; chain = i >> 5; rq = (i >> 3) & 3; us = i & 7; }
    const int rowbase = rq * 16;
    const int GA = chain ? 4 : 3;
    const int GAH = GA * 256;

    u64* h0 = (u64*)(wsb + OFF_H0) + (size_t)chain * (NS * 16384);
    u64* h1 = (u64*)(wsb + OFF_H1) + (size_t)chain * (NS * 16384);
    int* flg = (int*)(wsb + OFF_FLG) + (chain * 4 + rq) * 1024;

    const unsigned* W16 = (const unsigned*)(wsb + OFF_W16);
    const int ld = chain ? 1024 : 768;

    const int NC  = kind ? 128 : GA * 64;       // weight cols in slice
    const int WU4 = kind ? 64 * 128 : 32 * NC;  // uint4 count of W slice
    const int AQS = kind ? 256 : 128;           // A quad stride (uint4 / kp count)
    uint4* W4 = (uint4*)smem;
    uint4* A4 = (uint4*)(smem + (size_t)WU4 * 16);
    float* sG = (float*)(smem + (size_t)WU4 * 16 + (size_t)AQS * 4 * 16);
    __half* sAhh = (__half*)A4;

    // ---- one-time weight preload into LDS ----
    if (kind == 0) {
        const uint4* S = (const uint4*)(W16 + (chain ? oLU0 : oGU0));
        for (int idx = tid; idx < WU4; idx += 1024) {
            const int kpc = idx / NC, j = idx - kpc * NC;
            const int gcol = (j >> 6) * 256 + us * 64 + (j & 63);
            W4[idx] = S[(size_t)kpc * ld + gcol];
        }
    } else {
        const uint4* SW = (const uint4*)(W16 + (chain ? oLW1 : oGW1));
        const uint4* SU = (const uint4*)(W16 + (chain ? oLU1 : oGU1));
        for (int idx = tid; idx < WU4; idx += 1024) {
            const int kpc = idx >> 7, j = idx & 127;
            const int g4 = j >> 5, u = j & 31;
            const bool top = kpc < 32;          // K rows 0..255 = W1 (h0); else U1 (h1)
            int sg;
            if (chain) sg = g4;                 // LSTM: i,f,c,o both halves
            else if (top) sg = (g4 == 3) ? -1 : g4;            // GRU: z,r,xh from W1
            else sg = (g4 == 2) ? -1 : ((g4 == 3) ? 2 : g4);   // GRU: z,r,rh from U1
            uint4 v = {0u, 0u, 0u, 0u};
            if (sg >= 0) {
                const uint4* S = top ? SW : SU;
                v = S[(size_t)(top ? kpc : kpc - 32) * ld + sg * 256 + us * 32 + u];
            }
            W4[idx] = v;
        }
    }

    // ---- per-thread constants ----
    const int uu   = kind ? (tid & 31) : (tid & 63);     // update identity
    const int urow = kind ? (tid >> 5) : (tid >> 6);
    const bool upd = kind ? (tid < 512) : true;
    const int uuG  = kind ? (us * 32 + uu) : (us * 64 + uu);
    int len = 0; float b0 = 0, b1 = 0, b2 = 0, b3 = 0, ow = 0;
    if (upd) {
        len = lengths[rowbase + urow];
        if (kind == 0) {
            if (chain == 0) { b0 = gbr0[uuG]; b1 = gbr0[256 + uuG]; b2 = gbr0[512 + uuG]; }
        } else {
            if (chain == 0) {
                b0 = gbi1[uuG] + gbr1[uuG];
                b1 = gbi1[256 + uuG] + gbr1[256 + uuG];
                b2 = gbi1[512 + uuG];
                b3 = gbr1[512 + uuG];
            } else {
                b0 = lb1[uuG]; b1 = lb1[256 + uuG];
                b2 = lb1[512 + uuG]; b3 = lb1[768 + uuG];
            }
            ow = outW[chain * 256 + uuG];
        }
    }
    const float outb0 = outb[0];
    const float* P0 = (const float*)(wsb + (chain ? OFF_PL : OFF_PG));
    float hprev = 0.0f, creg = 0.0f;

    const int gc = kind ? (tid & 127) : (tid & 255);     // GEMM identity
    const int gq = kind ? (tid >> 7) : (tid >> 8);       // K-split: r0 4-way, r1 8-way (8 kpc each)
    const bool gact = kind ? true : (gc < NC);

    for (int i = tid; i < AQS * 4 * 4; i += 1024) ((unsigned*)A4)[i] = 0;   // h(-1)=0
    __syncthreads();

    for (int t = 0; t < Tt; ++t) {
        // ---- early P0 loads (r0): latency hides under poll+GEMM ----
        float p0r[4] = {0, 0, 0, 0};
        if (kind == 0) {
            const size_t pb = ((size_t)(rowbase + urow) * Tt + t) * GAH + uuG;
            #pragma unroll
            for (int g = 0; g < 4; ++g)
                if (g < GA) p0r[g] = P0[pb + g * 256];
        }

        // ---- phase 1: poll A operand ----
        if (kind == 0) {
            if (t > 0) {
                const u64* base = h0 + (size_t)((t - 1) & (NS - 1)) * 16384;
                const unsigned want = (unsigned)t;
                #pragma unroll
                for (int i = 0; i < 4; ++i) {
                    const int p = tid + i * 1024;
                    const int prow = p >> 8, pun = p & 255;
                    const float v = pollF(base + (rowbase + prow) * 256 + pun, want);
                    sAhh[(((prow >> 2) * 128 + (pun >> 1)) << 3) + ((prow & 3) << 1) + (pun & 1)]
                        = __float2half(v);
                }
            }
            __syncthreads();
            if (tid == 0 && t > 0) xrel(flg + (0 + us) * 32, t);
        } else {
            {   // h0(t), tag t+1 -> kp [0,128)
                const u64* base = h0 + (size_t)(t & (NS - 1)) * 16384;
                const unsigned want = (unsigned)(t + 1);
                #pragma unroll
                for (int i = 0; i < 4; ++i) {
                    const int p = tid + i * 1024;
                    const int prow = p >> 8, pun = p & 255;
                    const float v = pollF(base + (rowbase + prow) * 256 + pun, want);
                    sAhh[(((prow >> 2) * 256 + (pun >> 1)) << 3) + ((prow & 3) << 1) + (pun & 1)]
                        = __float2half(v);
                }
            }
            if (t > 0) {   // h1(t-1), tag t -> kp [128,256)
                const u64* base = h1 + (size_t)((t - 1) & (NS - 1)) * 16384;
                const unsigned want = (unsigned)t;
                #pragma unroll
                for (int i = 0; i < 4; ++i) {
                    const int p = tid + i * 1024;
                    const int prow = p >> 8, pun = p & 255;
                    const float v = pollF(base + (rowbase + prow) * 256 + pun, want);
                    sAhh[(((prow >> 2) * 256 + 128 + (pun >> 1)) << 3) + ((prow & 3) << 1) + (pun & 1)]
                        = __float2half(v);
                }
            }
            __syncthreads();
            if (tid == 0) {
                xrel(flg + (8 + us) * 32, t + 1);
                if (t > 0) xrel(flg + (16 + us) * 32, t);
            }
        }

        // ---- phase 2: GEMM from LDS weights (16 rows x col gc, K-slice) ----
        float4 a0 = {0,0,0,0}, a1 = a0, a2 = a0, a3 = a0;
        if (gact) {
            const uint4* Wc = W4 + gc;
            const int kpcB = gq * 8;
            for (int kpc = kpcB; kpc < kpcB + 8; ++kpc) {
                const uint4 w = Wc[(size_t)kpc * NC];
                fmaC(w, A4 + 0 * AQS, kpc * 4, a0);
                fmaC(w, A4 + 1 * AQS, kpc * 4, a1);
                fmaC(w, A4 + 2 * AQS, kpc * 4, a2);
                fmaC(w, A4 + 3 * AQS, kpc * 4, a3);
            }
        }
        // fold K-slices: gq==0 writes, others LDS-atomic-add
        if (gact && gq == 0) {
            sG[gc*16+ 0]=a0.x; sG[gc*16+ 1]=a0.y; sG[gc*16+ 2]=a0.z; sG[gc*16+ 3]=a0.w;
            sG[gc*16+ 4]=a1.x; sG[gc*16+ 5]=a1.y; sG[gc*16+ 6]=a1.z; sG[gc*16+ 7]=a1.w;
            sG[gc*16+ 8]=a2.x; sG[gc*16+ 9]=a2.y; sG[gc*16+10]=a2.z; sG[gc*16+11]=a2.w;
            sG[gc*16+12]=a3.x; sG[gc*16+13]=a3.y; sG[gc*16+14]=a3.z; sG[gc*16+15]=a3.w;
        }
        __syncthreads();
        if (gact && gq != 0) {
            atomicAdd(&sG[gc*16+ 0],a0.x); atomicAdd(&sG[gc*16+ 1],a0.y);
            atomicAdd(&sG[gc*16+ 2],a0.z); atomicAdd(&sG[gc*16+ 3],a0.w);
            atomicAdd(&sG[gc*16+ 4],a1.x); atomicAdd(&sG[gc*16+ 5],a1.y);
            atomicAdd(&sG[gc*16+ 6],a1.z); atomicAdd(&sG[gc*16+ 7],a1.w);
            atomicAdd(&sG[gc*16+ 8],a2.x); atomicAdd(&sG[gc*16+ 9],a2.y);
            atomicAdd(&sG[gc*16+10],a2.z); atomicAdd(&sG[gc*16+11],a2.w);
            atomicAdd(&sG[gc*16+12],a3.x); atomicAdd(&sG[gc*16+13],a3.y);
            atomicAdd(&sG[gc*16+14],a3.z); atomicAdd(&sG[gc*16+15],a3.w);
        }
        __syncthreads();

        // ---- phase 3: state update ----
        float hn = 0.0f;
        if (upd) {
            float Q[4] = {0, 0, 0, 0};
            if (kind == 0) {
                #pragma unroll
                for (int g = 0; g < 4; ++g)
                    if (g < GA) Q[g] = sG[((g << 6) + uu) * 16 + urow];
            } else {
                #pragma unroll
                for (int g = 0; g < 4; ++g)
                    Q[g] = sG[((g << 5) + uu) * 16 + urow];
            }
            const float hold = hprev;
            if (kind == 0) {
                if (chain == 0) {
                    const float z  = sigf(p0r[0] + Q[0] + b0);
                    const float r_ = sigf(p0r[1] + Q[1] + b1);
                    const float hh = tanhf(p0r[2] + r_ * (Q[2] + b2));
                    hn = z * hold + (1.0f - z) * hh;
                    if (t >= len) hn = hold;
                } else {
                    float cn = sigf(p0r[1] + Q[1]) * creg
                             + sigf(p0r[0] + Q[0]) * tanhf(p0r[2] + Q[2]);
                    hn = sigf(p0r[3] + Q[3]) * tanhf(cn);
                    if (t >= len) { hn = hold; cn = creg; }
                    creg = cn;
                }
            } else {
                if (chain == 0) {
                    const float z  = sigf(Q[0] + b0);
                    const float r_ = sigf(Q[1] + b1);
                    const float hh = tanhf(Q[2] + b2 + r_ * (Q[3] + b3));
                    hn = z * hold + (1.0f - z) * hh;
                    if (t >= len) hn = hold;
                } else {
                    float cn = sigf(Q[1] + b1) * creg
                             + sigf(Q[0] + b0) * tanhf(Q[2] + b2);
                    hn = sigf(Q[3] + b3) * tanhf(cn);
                    if (t >= len) { hn = hold; cn = creg; }
                    creg = cn;
                }
                // head partial: reduce 32 units -> atomicAdd per row
                float vh = hn * ow;
                #pragma unroll
                for (int o = 16; o > 0; o >>= 1) vh += __shfl_down(vh, o, 32);
                if ((tid & 31) == 0)
                    atomicAdd(&out[(size_t)(rowbase + urow) * Tt + t],
                              vh + ((chain == 1 && us == 0) ? outb0 : 0.0f));
            }
            hprev = hn;
        }

        // ---- anti-clobber wait + publish ----
        if (t >= NS) {
            if (tid == 0) {
                const int need = t - NS + 1;
                if (kind == 0) {
                    for (;;) {
                        int m = 0x7fffffff;
                        for (int f = 0; f < 4; ++f)  m = min(m, agldi(flg + f * 32));
                        for (int f = 8; f < 16; ++f) m = min(m, agldi(flg + f * 32));
                        if (m >= need) break;
                        __builtin_amdgcn_s_sleep(1);
                    }
                } else {
                    for (;;) {
                        int m = 0x7fffffff;
                        for (int f = 16; f < 24; ++f) m = min(m, agldi(flg + f * 32));
                        if (m >= need) break;
                        __builtin_amdgcn_s_sleep(1);
                    }
                }
            }
            __syncthreads();
        }
        if (upd) {
            u64* ring = kind ? h1 : h0;
            agst(ring + (size_t)(t & (NS - 1)) * 16384 + (rowbase + urow) * 256 + uuG,
                 ((u64)__float_as_uint(hn) << 32) | (unsigned)(t + 1));
        }
        __syncthreads();   // sAh/sG safe for next iteration
    }
}

extern "C" void kernel_launch(void* const* d_in, const int* in_sizes, int n_in,
                              void* d_out, int out_size, void* d_ws, size_t ws_size,
                              hipStream_t stream) {
    const float* x       = (const float*)d_in[0];
    const int*   lengths = (const int*)d_in[1];
    const float* gW0  = (const float*)d_in[2];
    const float* gU0  = (const float*)d_in[3];
    const float* gbi0 = (const float*)d_in[4];
    const float* gbr0 = (const float*)d_in[5];
    const float* gW1  = (const float*)d_in[6];
    const float* gU1  = (const float*)d_in[7];
    const float* gbi1 = (const float*)d_in[8];
    const float* gbr1 = (const float*)d_in[9];
    const float* lW0  = (const float*)d_in[10];
    const float* lU0  = (const float*)d_in[11];
    const float* lb0  = (const float*)d_in[12];
    const float* lW1  = (const float*)d_in[13];
    const float* lU1  = (const float*)d_in[14];
    const float* lb1  = (const float*)d_in[15];
    const float* outW = (const float*)d_in[16];
    const float* outb = (const float*)d_in[17];
    float* out = (float*)d_out;
    char* wsb  = (char*)d_ws;

    hipMemsetAsync(d_ws, 0, OFF_W16, stream);           // rings + flags
    hipMemsetAsync(d_out, 0, (size_t)out_size * sizeof(float), stream);

    unsigned* W16 = (unsigned*)(wsb + OFF_W16);
    struct { const float* s; size_t o; int K; int ld; } cv[8] = {
        {gW0, oGW0, 96, 768}, {gU0, oGU0, 256, 768},
        {gW1, oGW1, 256, 768}, {gU1, oGU1, 256, 768},
        {lW0, oLW0, 96, 1024}, {lU0, oLU0, 256, 1024},
        {lW1, oLW1, 256, 1024}, {lU1, oLU1, 256, 1024},
    };
    for (int i = 0; i < 8; ++i) {
        const int n = (cv[i].K / 2) * cv[i].ld;
        cvt_pair<<<(n + 255) / 256, 256, 0, stream>>>(cv[i].s, W16 + cv[i].o, n, cv[i].ld);
    }

    unsigned* XP = (unsigned*)(wsb + OFF_XP);
    const int nxp = 64 * Tt * 48;
    pack_x<<<(nxp + 255) / 256, 256, 0, stream>>>(x, XP);
    gemm_p0<<<dim3(1024), dim3(1024), 0, stream>>>(XP, gbi0, lb0, wsb);

    (void)hipFuncSetAttribute((const void*)rnn_fused,
                              hipFuncAttributeMaxDynamicSharedMemorySize, LDS_BYTES);
    rnn_fused<<<dim3(96), dim3(1024), LDS_BYTES, stream>>>(
        lengths, gbr0, gbi1, gbr1, lb1, outW, outb, out, wsb);
}

// Round 9
// 12406.168 us; speedup vs baseline: 1.2442x; 1.2442x over previous
//
#include <hip/hip_runtime.h>
#include <hip/hip_fp16.h>

// B=64, T=512, D=96, H=256
constexpr int Tt = 512, Dd = 96, Hh = 256;
constexpr int NS0 = 16;   // h0 ring depth
constexpr int NS1 = 16;   // h1 ring depth
constexpr int NSP = 8;    // P ring depth
typedef unsigned long long u64;

// workspace layout
constexpr size_t OFF_H0  = 0;                                   // 32grp x 16x1024 u64 = 4MB
constexpr size_t OFF_P0  = (size_t)4 << 20;                     // 32grp x 8x4096 u64 = 8MB
constexpr size_t OFF_P1  = (size_t)12 << 20;                    // 8MB
constexpr size_t OFF_H1  = (size_t)20 << 20;                    // 4MB
constexpr size_t OFF_FLG = (size_t)24 << 20;                    // 32grp x 16 x 32 ints = 64KB
constexpr size_t OFF_W16 = ((size_t)24 << 20) + ((size_t)64 << 10);
constexpr size_t oGW0 = 0;
constexpr size_t oGU0 = oGW0 + (size_t)48 * 768;
constexpr size_t oGW1 = oGU0 + (size_t)128 * 768;
constexpr size_t oGU1 = oGW1 + (size_t)128 * 768;
constexpr size_t oLW0 = oGU1 + (size_t)128 * 768;
constexpr size_t oLU0 = oLW0 + (size_t)48 * 1024;
constexpr size_t oLW1 = oLU0 + (size_t)128 * 1024;
constexpr size_t oLU1 = oLW1 + (size_t)128 * 1024;

__device__ __forceinline__ float sigf(float v) { return 1.0f / (1.0f + __expf(-v)); }
__device__ __forceinline__ u64 agld(const u64* p) {
    return __hip_atomic_load(p, __ATOMIC_RELAXED, __HIP_MEMORY_SCOPE_AGENT);
}
__device__ __forceinline__ int agldi(const int* p) {
    return __hip_atomic_load(p, __ATOMIC_ACQUIRE, __HIP_MEMORY_SCOPE_AGENT);
}
__device__ __forceinline__ void agst(u64* p, u64 v) {
    __hip_atomic_store(p, v, __ATOMIC_RELAXED, __HIP_MEMORY_SCOPE_AGENT);
}
__device__ __forceinline__ void xrel(int* p, int v) {
    __hip_atomic_exchange(p, v, __ATOMIC_RELEASE, __HIP_MEMORY_SCOPE_AGENT);
}
__device__ __forceinline__ float pollF(const u64* p, unsigned want) {
    u64 v = agld(p);
    while ((unsigned)v != want) v = agld(p);
    return __uint_as_float((unsigned)(v >> 32));
}

// fp16x2 dot into f32 accumulator (v_dot2_f32_f16)
__device__ __forceinline__ float dot2f(unsigned w, unsigned a, float acc) {
#if __has_builtin(__builtin_amdgcn_fdot2)
    typedef _Float16 h2v __attribute__((ext_vector_type(2)));
    h2v wh, ah;
    __builtin_memcpy(&wh, &w, 4);
    __builtin_memcpy(&ah, &a, 4);
    return __builtin_amdgcn_fdot2(wh, ah, acc, false);
#else
    const float2 wf = __half22float2(*(const __half2*)&w);
    const float2 af = __half22float2(*(const __half2*)&a);
    acc = fmaf(wf.x, af.x, acc);
    return fmaf(wf.y, af.y, acc);
#endif
}

// LDS A layout: uint4 per kp; .x/.y/.z/.w = rows 0..3, each a half2 (k=2kp, 2kp+1)
__device__ __forceinline__ int hidx(int k, int r) {
    return (k >> 1) * 8 + r * 2 + (k & 1);   // half index into sAh
}

// ---- fp16-pair GEMM, 4-kp chunks, depth-2 pipeline (R6-identical) ----
template<int G>
__device__ __forceinline__ void load4h(uint4* wv, const uint4* __restrict__ M4,
                                       int ldm, int kpb) {
    const int base = (kpb >> 2) * ldm;
    #pragma unroll
    for (int g = 0; g < G; ++g)
        wv[g] = M4[base + g * 256];
}
template<int G>
__device__ __forceinline__ void fma4h(const uint4* wv, const uint4* __restrict__ A4,
                                      int kpb, float4* acc) {
    const uint4 a0 = A4[kpb + 0];
    const uint4 a1 = A4[kpb + 1];
    const uint4 a2 = A4[kpb + 2];
    const uint4 a3 = A4[kpb + 3];
    #pragma unroll
    for (int g = 0; g < G; ++g) {
        const uint4 w = wv[g];
        acc[g].x = dot2f(w.x, a0.x, acc[g].x);
        acc[g].y = dot2f(w.x, a0.y, acc[g].y);
        acc[g].z = dot2f(w.x, a0.z, acc[g].z);
        acc[g].w = dot2f(w.x, a0.w, acc[g].w);
        acc[g].x = dot2f(w.y, a1.x, acc[g].x);
        acc[g].y = dot2f(w.y, a1.y, acc[g].y);
        acc[g].z = dot2f(w.y, a1.z, acc[g].z);
        acc[g].w = dot2f(w.y, a1.w, acc[g].w);
        acc[g].x = dot2f(w.z, a2.x, acc[g].x);
        acc[g].y = dot2f(w.z, a2.y, acc[g].y);
        acc[g].z = dot2f(w.z, a2.z, acc[g].z);
        acc[g].w = dot2f(w.z, a2.w, acc[g].w);
        acc[g].x = dot2f(w.w, a3.x, acc[g].x);
        acc[g].y = dot2f(w.w, a3.y, acc[g].y);
        acc[g].z = dot2f(w.w, a3.z, acc[g].z);
        acc[g].w = dot2f(w.w, a3.w, acc[g].w);
    }
}
template<int G>
__device__ __forceinline__ void gemmP(const uint4* __restrict__ M4, int ldm,
                                      const uint4* __restrict__ A4,
                                      int kp0, int kp1, float4* acc) {
    const int n4 = (kp1 - kp0) >> 2;
    uint4 wv0[G], wv1[G];
    if (n4 <= 0) return;
    load4h<G>(wv0, M4, ldm, kp0);
    int c2 = 0;
    for (; c2 + 2 <= n4; c2 += 2) {
        load4h<G>(wv1, M4, ldm, kp0 + (c2 + 1) * 4);
        fma4h<G>(wv0, A4, kp0 + c2 * 4, acc);
        if (c2 + 2 < n4) load4h<G>(wv0, M4, ldm, kp0 + (c2 + 2) * 4);
        fma4h<G>(wv1, A4, kp0 + (c2 + 1) * 4, acc);
    }
    if (c2 < n4) fma4h<G>(wv0, A4, kp0 + c2 * 4, acc);
}

// weight f32 -> paired fp16, chunk-tiled transposed layout (per launch)
__global__ void cvt_pair(const float* __restrict__ src, unsigned* __restrict__ dst,
                         int n, int ld) {
    const int i = blockIdx.x * 256 + threadIdx.x;
    if (i >= n) return;
    const int kp = i / ld, col = i - kp * ld;
    const __half2 h = __floats2half2_rn(src[(2 * kp) * ld + col],
                                        src[(2 * kp + 1) * ld + col]);
    dst[((size_t)((kp >> 2) * ld + col) << 2) + (kp & 3)] = *(const unsigned*)&h;
}

// ============ R9: column-split pipeline ============
// 224 blocks: bx = grpid*7 + sub; grpid = chain*16+rg.
// sub 0 = p0 (unsplit, R6 role-0); sub 1,2 = r0 halves; 3,4 = p1 halves; 5,6 = r1 halves.
// flags per grpid (f*32 ints): 0,1 P0 consumed by r0h; 2,3 h0 consumed by p1h;
// 4,5 h0(t-1) consumed by r0 peer; 6,7 P1 consumed by r1h; 8,9 h1(t-1) consumed by r1 peer.
__global__ void __launch_bounds__(1024, 4)
rnn_split(const float* __restrict__ x, const int* __restrict__ lengths,
          const float* __restrict__ gbi0, const float* __restrict__ gbr0,
          const float* __restrict__ gbi1, const float* __restrict__ gbr1,
          const float* __restrict__ lb0, const float* __restrict__ lb1,
          const float* __restrict__ outW, const float* __restrict__ outb,
          float* __restrict__ out, char* __restrict__ wsb)
{
    const int tid = threadIdx.x;
    const int bx  = blockIdx.x;
    const int grpid = bx / 7;
    const int sub   = bx - grpid * 7;
    const int chain = grpid >> 4;
    const int rg    = grpid & 15;
    const int rowbase = rg * 4;
    const int kind = (sub == 0) ? 0 : 1 + ((sub - 1) >> 1);   // 0 p0, 1 r0, 2 p1, 3 r1
    const int half = (sub == 0) ? 0 : ((sub - 1) & 1);

    const int GA  = chain ? 4 : 3;
    const int GAH = GA * Hh;
    const int RS  = GA * 128;                 // half-fold row stride

    u64* h0ring = (u64*)(wsb + OFF_H0) + (size_t)grpid * (NS0 * 1024);
    u64* p0ring = (u64*)(wsb + OFF_P0) + (size_t)grpid * (NSP * 4096);
    u64* p1ring = (u64*)(wsb + OFF_P1) + (size_t)grpid * (NSP * 4096);
    u64* h1ring = (u64*)(wsb + OFF_H1) + (size_t)grpid * (NS1 * 1024);
    int* flg = (int*)(wsb + OFF_FLG) + grpid * (16 * 32);
    #define F(i) (flg + (i) * 32)

    const unsigned* W16 = (const unsigned*)(wsb + OFF_W16);
    size_t woff;
    if (chain == 0) woff = (kind == 0) ? oGW0 : (kind == 1) ? oGU0 : (kind == 2) ? oGW1 : oGU1;
    else            woff = (kind == 0) ? oLW0 : (kind == 1) ? oLU0 : (kind == 2) ? oLW1 : oLU1;
    const int c256 = tid & 255, c128 = tid & 127;
    const int grp4 = tid >> 8, grp8 = tid >> 7;
    const uint4* M4 = (const uint4*)(W16 + woff)
                      + ((kind == 0) ? c256 : (half * 128 + c128));
    const int kp0 = (kind == 0) ? grp4 * 12 : grp8 * 16;
    const int kp1 = kp0 + ((kind == 0) ? 12 : 16);

    __shared__ __align__(16) unsigned sAh[128 * 4];   // A operand: 128 kp x 4 rows
    __shared__ float sG[8192];                        // fold buffers
    __shared__ float sRed[16];
    __half* sAhh = (__half*)sAh;
    const uint4* A4 = (const uint4*)sAh;

    // ---- p0 publish precompute (R6) ----
    const int NP = 4 * GAH;
    const int npt0 = NP >> 10;                        // 3 or 4
    float biasv[4]; int sgidx[4], ringoff[4];
    if (kind == 0) {
        const float* bsrc = chain ? lb0 : gbi0;
        #pragma unroll
        for (int i = 0; i < 4; ++i) {
            if (i < npt0) {
                const int e = tid + i * 1024;
                const int r = e / GAH, rem = e - r * GAH;
                biasv[i] = bsrc[rem]; sgidx[i] = r * 1024 + rem; ringoff[i] = e;
            } else { biasv[i] = 0; sgidx[i] = 0; ringoff[i] = 0; }
        }
    } else if (kind == 2) {
        // p1-half publish: NPh = 4*GA*128 words
        const float* bsrc = chain ? lb1 : gbi1;
        const int NPh = 4 * GA * 128;
        #pragma unroll
        for (int i = 0; i < 2; ++i) {
            const int e = tid + i * 1024;
            if (e < NPh) {
                const int u = e & 127, rest = e >> 7;
                const int r = rest / GA, g = rest - r * GA;
                biasv[i]   = bsrc[g * 256 + half * 128 + u];
                sgidx[i]   = r * RS + g * 128 + u;
                ringoff[i] = r * GAH + g * 256 + half * 128 + u;
            } else { biasv[i] = 0; sgidx[i] = -1; ringoff[i] = 0; }
        }
    }

    // ---- r-half update identity (tid<512) ----
    const int uu = tid & 127, urow = (tid >> 7) & 3;
    const bool upd = (kind == 1 || kind == 3) && tid < 512;
    const int ucol = half * 128 + uu;
    int len = Tt + 1;
    float brz = 0, brr = 0, brh = 0, ow = 0;
    if (upd) {
        len = lengths[rowbase + urow];
        if (chain == 0) {
            const float* br = (kind == 1) ? gbr0 : gbr1;
            brz = br[ucol]; brr = br[256 + ucol]; brh = br[512 + ucol];
        }
        if (kind == 3) ow = outW[chain * Hh + ucol];
    }
    const float outb0 = outb[0];
    float creg = 0.0f, hprev = 0.0f;

    for (int i = tid; i < 512; i += 1024) sAh[i] = 0;   // h(-1)=0
    __syncthreads();

    for (int t = 0; t < Tt; ++t) {
        // ============ phase A: acquire A operand ============
        if (kind == 0) {
            if (t >= NSP) {
                if (tid == 0)
                    while (min(agldi(F(0)), agldi(F(1))) < t - NSP + 1)
                        __builtin_amdgcn_s_sleep(1);
                __syncthreads();
            }
            if (tid < 4 * Dd) {
                const int r = tid / Dd, k = tid - r * Dd;
                sAhh[hidx(k, r)] =
                    __float2half(x[((size_t)(rowbase + r) * Tt + t) * Dd + k]);
            }
            __syncthreads();
        } else if (kind == 1 || kind == 3) {
            if (t > 0 && tid < 512) {   // peer half of h(t-1), tag t
                const u64* ring = (kind == 1) ? h0ring : h1ring;
                const u64* base = ring + (size_t)((t - 1) & (NS0 - 1)) * 1024;
                const int k = (1 - half) * 128 + uu;
                const float v = pollF(base + urow * 256 + k, (unsigned)t);
                sAhh[hidx(k, urow)] = __float2half(v);
            }
            __syncthreads();
        } else {   // p1: full h0(t), tag t+1
            const int un = tid & 255, r = tid >> 8;
            const float v = pollF(h0ring + (size_t)(t & (NS0 - 1)) * 1024 + r * 256 + un,
                                  (unsigned)(t + 1));
            sAhh[hidx(un, r)] = __float2half(v);
            __syncthreads();
            if (tid == 0) xrel(F(2 + half), t + 1);
        }

        // ============ phase B: GEMM + fold ============
        if (kind == 0) {
            if (chain == 0) {
                float4 acc[3] = {{0,0,0,0},{0,0,0,0},{0,0,0,0}};
                gemmP<3>(M4, GAH, A4, kp0, kp1, acc);
                if (grp4 < 2) {
                    #pragma unroll
                    for (int g = 0; g < 3; ++g) {
                        sG[grp4 * 4096 + 0 + g * 256 + c256]    = acc[g].x;
                        sG[grp4 * 4096 + 1024 + g * 256 + c256] = acc[g].y;
                        sG[grp4 * 4096 + 2048 + g * 256 + c256] = acc[g].z;
                        sG[grp4 * 4096 + 3072 + g * 256 + c256] = acc[g].w;
                    }
                }
                __syncthreads();
                if (grp4 >= 2) {
                    const int b = (grp4 - 2) * 4096;
                    #pragma unroll
                    for (int g = 0; g < 3; ++g) {
                        sG[b + 0 + g * 256 + c256]    += acc[g].x;
                        sG[b + 1024 + g * 256 + c256] += acc[g].y;
                        sG[b + 2048 + g * 256 + c256] += acc[g].z;
                        sG[b + 3072 + g * 256 + c256] += acc[g].w;
                    }
                }
            } else {
                float4 acc[4] = {{0,0,0,0},{0,0,0,0},{0,0,0,0},{0,0,0,0}};
                gemmP<4>(M4, GAH, A4, kp0, kp1, acc);
                if (grp4 < 2) {
                    #pragma unroll
                    for (int g = 0; g < 4; ++g) {
                        sG[grp4 * 4096 + 0 + g * 256 + c256]    = acc[g].x;
                        sG[grp4 * 4096 + 1024 + g * 256 + c256] = acc[g].y;
                        sG[grp4 * 4096 + 2048 + g * 256 + c256] = acc[g].z;
                        sG[grp4 * 4096 + 3072 + g * 256 + c256] = acc[g].w;
                    }
                }
                __syncthreads();
                if (grp4 >= 2) {
                    const int b = (grp4 - 2) * 4096;
                    #pragma unroll
                    for (int g = 0; g < 4; ++g) {
                        sG[b + 0 + g * 256 + c256]    += acc[g].x;
                        sG[b + 1024 + g * 256 + c256] += acc[g].y;
                        sG[b + 2048 + g * 256 + c256] += acc[g].z;
                        sG[b + 3072 + g * 256 + c256] += acc[g].w;
                    }
                }
            }
        } else {
            if (chain == 0) {
                float4 acc[3] = {{0,0,0,0},{0,0,0,0},{0,0,0,0}};
                gemmP<3>(M4, GAH, A4, kp0, kp1, acc);
                if (grp8 < 4) {
                    const int b = grp8 * 2048;
                    #pragma unroll
                    for (int g = 0; g < 3; ++g) {
                        sG[b + 0 * RS + g * 128 + c128] = acc[g].x;
                        sG[b + 1 * RS + g * 128 + c128] = acc[g].y;
                        sG[b + 2 * RS + g * 128 + c128] = acc[g].z;
                        sG[b + 3 * RS + g * 128 + c128] = acc[g].w;
                    }
                }
                __syncthreads();
                if (grp8 >= 4) {
                    const int b = (grp8 - 4) * 2048;
                    #pragma unroll
                    for (int g = 0; g < 3; ++g) {
                        sG[b + 0 * RS + g * 128 + c128] += acc[g].x;
                        sG[b + 1 * RS + g * 128 + c128] += acc[g].y;
                        sG[b + 2 * RS + g * 128 + c128] += acc[g].z;
                        sG[b + 3 * RS + g * 128 + c128] += acc[g].w;
                    }
                }
            } else {
                float4 acc[4] = {{0,0,0,0},{0,0,0,0},{0,0,0,0},{0,0,0,0}};
                gemmP<4>(M4, GAH, A4, kp0, kp1, acc);
                if (grp8 < 4) {
                    const int b = grp8 * 2048;
                    #pragma unroll
                    for (int g = 0; g < 4; ++g) {
                        sG[b + 0 * RS + g * 128 + c128] = acc[g].x;
                        sG[b + 1 * RS + g * 128 + c128] = acc[g].y;
                        sG[b + 2 * RS + g * 128 + c128] = acc[g].z;
                        sG[b + 3 * RS + g * 128 + c128] = acc[g].w;
                    }
                }
                __syncthreads();
                if (grp8 >= 4) {
                    const int b = (grp8 - 4) * 2048;
                    #pragma unroll
                    for (int g = 0; g < 4; ++g) {
                        sG[b + 0 * RS + g * 128 + c128] += acc[g].x;
                        sG[b + 1 * RS + g * 128 + c128] += acc[g].y;
                        sG[b + 2 * RS + g * 128 + c128] += acc[g].z;
                        sG[b + 3 * RS + g * 128 + c128] += acc[g].w;
                    }
                }
            }
        }
        __syncthreads();

        // ============ phase C: publish / update ============
        if (kind == 0) {
            u64* slot = p0ring + (size_t)(t & (NSP - 1)) * 4096;
            for (int i = 0; i < npt0; ++i) {
                const float v = sG[sgidx[i]] + sG[4096 + sgidx[i]] + biasv[i];
                agst(slot + ringoff[i],
                     ((u64)__float_as_uint(v) << 32) | (unsigned)(t + 1));
            }
        } else if (kind == 2) {
            if (t >= NSP) {
                if (tid == 0)
                    while (min(agldi(F(6)), agldi(F(7))) < t - NSP + 1)
                        __builtin_amdgcn_s_sleep(1);
                __syncthreads();
            }
            u64* slot = p1ring + (size_t)(t & (NSP - 1)) * 4096;
            #pragma unroll
            for (int i = 0; i < 2; ++i) {
                if (sgidx[i] >= 0) {
                    const float v = sG[sgidx[i]] + sG[2048 + sgidx[i]]
                                  + sG[4096 + sgidx[i]] + sG[6144 + sgidx[i]] + biasv[i];
                    agst(slot + ringoff[i],
                         ((u64)__float_as_uint(v) << 32) | (unsigned)(t + 1));
                }
            }
        } else {
            // r0 / r1 half: direct-register poll of P, then update
            float hn = 0.0f, vh = 0.0f;
            if (upd) {
                const u64* slot = ((kind == 1) ? p0ring : p1ring)
                                  + (size_t)(t & (NSP - 1)) * 4096 + urow * GAH + ucol;
                const unsigned want = (unsigned)(t + 1);
                float P_[4] = {0, 0, 0, 0};
                unsigned dm = 0;
                const unsigned full = (1u << GA) - 1u;
                while (dm != full) {
                    #pragma unroll
                    for (int g = 0; g < 4; ++g) {
                        if (g < GA && !(dm & (1u << g))) {
                            const u64 v = agld(slot + g * 256);
                            if ((unsigned)v == want) {
                                P_[g] = __uint_as_float((unsigned)(v >> 32));
                                dm |= 1u << g;
                            }
                        }
                    }
                }
                const int qb = urow * RS + uu;
                float Q[4] = {0, 0, 0, 0};
                #pragma unroll
                for (int g = 0; g < 4; ++g)
                    if (g < GA)
                        Q[g] = sG[qb + g * 128] + sG[2048 + qb + g * 128]
                             + sG[4096 + qb + g * 128] + sG[6144 + qb + g * 128];
                const float hold = hprev;
                if (chain == 0) {
                    const float z  = sigf(P_[0] + Q[0] + brz);
                    const float r_ = sigf(P_[1] + Q[1] + brr);
                    const float hh = tanhf(P_[2] + r_ * (Q[2] + brh));
                    hn = z * hold + (1.0f - z) * hh;
                    if (t >= len) hn = hold;
                } else {
                    float cn = sigf(P_[1] + Q[1]) * creg
                             + sigf(P_[0] + Q[0]) * tanhf(P_[2] + Q[2]);
                    hn = sigf(P_[3] + Q[3]) * tanhf(cn);
                    if (t >= len) { hn = hold; cn = creg; }
                    creg = cn;
                }
                hprev = hn;
                sAhh[hidx(ucol, urow)] = __float2half(hn);   // own half for next GEMM
                if (kind == 3) vh = hn * ow;
            }
            if (kind == 3) {
                if (upd) {
                    #pragma unroll
                    for (int o = 32; o > 0; o >>= 1) vh += __shfl_down(vh, o);
                    if ((tid & 63) == 0) sRed[tid >> 6] = vh;   // 8 waves
                }
                __syncthreads();
                if (tid < 4) {
                    const float s = sRed[2 * tid] + sRed[2 * tid + 1];
                    atomicAdd(&out[(size_t)(rowbase + tid) * Tt + t],
                              s + ((chain == 1 && half == 0) ? outb0 : 0.0f));
                }
            }
            // anti-clobber for own h ring, then publish
            const int NSH = (kind == 1) ? NS0 : NS1;
            if (t >= NSH) {
                if (tid == 0) {
                    int need = t - NSH + 1;
                    if (kind == 1) {
                        while (min(min(agldi(F(2)), agldi(F(3))),
                                   min(agldi(F(4)), agldi(F(5)))) < need)
                            __builtin_amdgcn_s_sleep(1);
                    } else {
                        while (min(agldi(F(8)), agldi(F(9))) < need)
                            __builtin_amdgcn_s_sleep(1);
                    }
                }
                __syncthreads();
            }
            if (upd) {
                u64* ring = (kind == 1) ? h0ring : h1ring;
                agst(ring + (size_t)(t & (NS0 - 1)) * 1024 + urow * 256 + ucol,
                     ((u64)__float_as_uint(hn) << 32) | (unsigned)(t + 1));
            }
        }
        __syncthreads();   // sAh/sG/sRed safe; all polls complete
        if (tid == 0) {
            if (kind == 1) {
                xrel(F(0 + half), t + 1);   // P0 slot t consumed
                xrel(F(4 + half), t);       // peer h0(t-1) consumed
            } else if (kind == 3) {
                xrel(F(6 + half), t + 1);   // P1 slot t consumed
                xrel(F(8 + half), t);       // peer h1(t-1) consumed
            }
        }
    }
    #undef F
}

extern "C" void kernel_launch(void* const* d_in, const int* in_sizes, int n_in,
                              void* d_out, int out_size, void* d_ws, size_t ws_size,
                              hipStream_t stream) {
    const float* x       = (const float*)d_in[0];
    const int*   lengths = (const int*)d_in[1];
    const float* gW0  = (const float*)d_in[2];
    const float* gU0  = (const float*)d_in[3];
    const float* gbi0 = (const float*)d_in[4];
    const float* gbr0 = (const float*)d_in[5];
    const float* gW1  = (const float*)d_in[6];
    const float* gU1  = (const float*)d_in[7];
    const float* gbi1 = (const float*)d_in[8];
    const float* gbr1 = (const float*)d_in[9];
    const float* lW0  = (const float*)d_in[10];
    const float* lU0  = (const float*)d_in[11];
    const float* lb0  = (const float*)d_in[12];
    const float* lW1  = (const float*)d_in[13];
    const float* lU1  = (const float*)d_in[14];
    const float* lb1  = (const float*)d_in[15];
    const float* outW = (const float*)d_in[16];
    const float* outb = (const float*)d_in[17];
    float* out = (float*)d_out;
    char* wsb  = (char*)d_ws;

    hipMemsetAsync(d_ws, 0, OFF_W16, stream);   // rings + flags
    hipMemsetAsync(d_out, 0, (size_t)out_size * sizeof(float), stream);

    unsigned* W16 = (unsigned*)(wsb + OFF_W16);
    struct { const float* s; size_t o; int K; int ld; } cv[8] = {
        {gW0, oGW0, 96, 768}, {gU0, oGU0, 256, 768},
        {gW1, oGW1, 256, 768}, {gU1, oGU1, 256, 768},
        {lW0, oLW0, 96, 1024}, {lU0, oLU0, 256, 1024},
        {lW1, oLW1, 256, 1024}, {lU1, oLU1, 256, 1024},
    };
    for (int i = 0; i < 8; ++i) {
        const int n = (cv[i].K / 2) * cv[i].ld;
        cvt_pair<<<(n + 255) / 256, 256, 0, stream>>>(cv[i].s, W16 + cv[i].o, n, cv[i].ld);
    }

    rnn_split<<<dim3(224), dim3(1024), 0, stream>>>(
        x, lengths, gbi0, gbr0, gbi1, gbr1, lb0, lb1, outW, outb, out, wsb);
}

// Round 10
// 5431.278 us; speedup vs baseline: 2.8421x; 2.2842x over previous
//
#include <hip/hip_runtime.h>
#include <hip/hip_fp16.h>

// B=64, T=512, D=96, H=256
constexpr int Tt = 512, Dd = 96, Hh = 256;
constexpr int NS0 = 16;   // h0 ring depth
constexpr int NSP = 8;    // P ring depth
typedef unsigned long long u64;

// ws byte offsets (R6-identical):
constexpr size_t OFF_P0  = (size_t)4 << 20;
constexpr size_t OFF_P1  = (size_t)12 << 20;
constexpr size_t OFF_FLG = (size_t)20 << 20;
constexpr size_t OFF_W16 = ((size_t)20 << 20) + ((size_t)64 << 10);
constexpr size_t oGW0 = 0;
constexpr size_t oGU0 = oGW0 + (size_t)48 * 768;
constexpr size_t oGW1 = oGU0 + (size_t)128 * 768;
constexpr size_t oGU1 = oGW1 + (size_t)128 * 768;
constexpr size_t oLW0 = oGU1 + (size_t)128 * 768;
constexpr size_t oLU0 = oLW0 + (size_t)48 * 1024;
constexpr size_t oLW1 = oLU0 + (size_t)128 * 1024;
constexpr size_t oLU1 = oLW1 + (size_t)128 * 1024;

// dynamic LDS layout: sAh (2048B) | sG 4 buffers x 4096 floats (65536B) | sRed (64B)
constexpr int SMEM_BYTES = 2048 + 65536 + 64;

__device__ __forceinline__ float sigf(float v) { return 1.0f / (1.0f + __expf(-v)); }
__device__ __forceinline__ u64 agld(const u64* p) {
    return __hip_atomic_load(p, __ATOMIC_RELAXED, __HIP_MEMORY_SCOPE_AGENT);
}
__device__ __forceinline__ int agldi(const int* p) {
    return __hip_atomic_load(p, __ATOMIC_ACQUIRE, __HIP_MEMORY_SCOPE_AGENT);
}
__device__ __forceinline__ void agst(u64* p, u64 v) {
    __hip_atomic_store(p, v, __ATOMIC_RELAXED, __HIP_MEMORY_SCOPE_AGENT);
}

// fp16x2 dot into f32 accumulator (v_dot2_f32_f16)
__device__ __forceinline__ float dot2f(unsigned w, unsigned a, float acc) {
#if __has_builtin(__builtin_amdgcn_fdot2)
    typedef _Float16 h2v __attribute__((ext_vector_type(2)));
    h2v wh, ah;
    __builtin_memcpy(&wh, &w, 4);
    __builtin_memcpy(&ah, &a, 4);
    return __builtin_amdgcn_fdot2(wh, ah, acc, false);
#else
    const float2 wf = __half22float2(*(const __half2*)&w);
    const float2 af = __half22float2(*(const __half2*)&a);
    acc = fmaf(wf.x, af.x, acc);
    return fmaf(wf.y, af.y, acc);
#endif
}

// LDS A layout: uint4 per kp; .x/.y/.z/.w = rows 0..3, each a half2 (k=2kp, 2kp+1)
__device__ __forceinline__ int hidx(int k, int r) {
    return (k >> 1) * 8 + r * 2 + (k & 1);   // half index into sAh
}

// ---- fp16-pair GEMM, 4-kp chunks, depth-2 pipeline (R6-identical) ----
template<int G>
__device__ __forceinline__ void load4h(uint4* wv, const uint4* __restrict__ M4,
                                       int ldm, int kpb) {
    const int base = (kpb >> 2) * ldm;
    #pragma unroll
    for (int g = 0; g < G; ++g)
        wv[g] = M4[base + g * 256];
}
template<int G>
__device__ __forceinline__ void fma4h(const uint4* wv, const uint4* __restrict__ A4,
                                      int kpb, float4* acc) {
    const uint4 a0 = A4[kpb + 0];
    const uint4 a1 = A4[kpb + 1];
    const uint4 a2 = A4[kpb + 2];
    const uint4 a3 = A4[kpb + 3];
    #pragma unroll
    for (int g = 0; g < G; ++g) {
        const uint4 w = wv[g];
        acc[g].x = dot2f(w.x, a0.x, acc[g].x);
        acc[g].y = dot2f(w.x, a0.y, acc[g].y);
        acc[g].z = dot2f(w.x, a0.z, acc[g].z);
        acc[g].w = dot2f(w.x, a0.w, acc[g].w);
        acc[g].x = dot2f(w.y, a1.x, acc[g].x);
        acc[g].y = dot2f(w.y, a1.y, acc[g].y);
        acc[g].z = dot2f(w.y, a1.z, acc[g].z);
        acc[g].w = dot2f(w.y, a1.w, acc[g].w);
        acc[g].x = dot2f(w.z, a2.x, acc[g].x);
        acc[g].y = dot2f(w.z, a2.y, acc[g].y);
        acc[g].z = dot2f(w.z, a2.z, acc[g].z);
        acc[g].w = dot2f(w.z, a2.w, acc[g].w);
        acc[g].x = dot2f(w.w, a3.x, acc[g].x);
        acc[g].y = dot2f(w.w, a3.y, acc[g].y);
        acc[g].z = dot2f(w.w, a3.z, acc[g].z);
        acc[g].w = dot2f(w.w, a3.w, acc[g].w);
    }
}
template<int G>
__device__ __forceinline__ void gemmP(const uint4* __restrict__ M4, int ldm,
                                      const uint4* __restrict__ A4,
                                      int kp0, int kp1, float4* acc) {
    const int n4 = (kp1 - kp0) >> 2;
    uint4 wv0[G], wv1[G];
    if (n4 <= 0) return;
    load4h<G>(wv0, M4, ldm, kp0);
    int c2 = 0;
    for (; c2 + 2 <= n4; c2 += 2) {
        load4h<G>(wv1, M4, ldm, kp0 + (c2 + 1) * 4);
        fma4h<G>(wv0, A4, kp0 + c2 * 4, acc);
        if (c2 + 2 < n4) load4h<G>(wv0, M4, ldm, kp0 + (c2 + 2) * 4);
        fma4h<G>(wv1, A4, kp0 + (c2 + 1) * 4, acc);
    }
    if (c2 < n4) fma4h<G>(wv0, A4, kp0 + c2 * 4, acc);
}

// weight f32 -> paired fp16, chunk-tiled transposed layout (per launch)
__global__ void cvt_pair(const float* __restrict__ src, unsigned* __restrict__ dst,
                         int n, int ld) {
    const int i = blockIdx.x * 256 + threadIdx.x;
    if (i >= n) return;
    const int kp = i / ld, col = i - kp * ld;
    const __half2 h = __floats2half2_rn(src[(2 * kp) * ld + col],
                                        src[(2 * kp + 1) * ld + col]);
    dst[((size_t)((kp >> 2) * ld + col) << 2) + (kp & 3)] = *(const unsigned*)&h;
}

// roles: 0 = p0 (x->P0), 1 = r0 (U0 + h0 update), 2 = p1 (h0->P1), 3 = r1 (U1 + head)
// bx = (chain*4+role) + 8*rg.   1024 threads: grp = tid>>8 (4-way K), c = tid&255.
// R10 vs R6: (a) 4 private fold buffers + ONE barrier (was 2-buffer RMW + 2 barriers);
//            (b) r-roles probe their P ring words BEFORE the GEMM (overlap HBM RT).
__global__ void __launch_bounds__(1024, 4)
rnn_persist(const float* __restrict__ x, const int* __restrict__ lengths,
            const float* __restrict__ gbi0, const float* __restrict__ gbr0,
            const float* __restrict__ gbi1, const float* __restrict__ gbr1,
            const float* __restrict__ lb0, const float* __restrict__ lb1,
            const float* __restrict__ outW, const float* __restrict__ outb,
            float* __restrict__ out, char* __restrict__ wsb)
{
    extern __shared__ __align__(16) char smem[];
    unsigned* sAh = (unsigned*)smem;                       // 512 u32
    float* sG   = (float*)(smem + 2048);                   // 4 x 4096 floats
    float* sRed = (float*)(smem + 2048 + 65536);           // 16 floats
    __half* sAhh = (__half*)sAh;
    const uint4* A4 = (const uint4*)sAh;

    const int tid = threadIdx.x;
    const int c   = tid & 255;
    const int grp = tid >> 8;                // 0..3
    const int bx  = blockIdx.x;
    const int role  = bx & 3;
    const int chain = (bx >> 2) & 1;
    const int rg    = bx >> 3;
    const int rowbase = rg * 4;

    const int GA  = chain ? 4 : 3;
    const int GAH = GA * Hh;

    u64* h0ring = (u64*)wsb + (size_t)(chain * 16 + rg) * (NS0 * 1024);
    u64* p0ring = (u64*)(wsb + OFF_P0) + (size_t)(chain * 16 + rg) * (NSP * 4096);
    u64* p1ring = (u64*)(wsb + OFF_P1) + (size_t)(chain * 16 + rg) * (NSP * 4096);
    int* flags = (int*)(wsb + OFF_FLG);
    int* flg_r0 = flags + ((chain * 16 + rg) * 4 + 1) * 32;
    int* flg_p1 = flags + ((chain * 16 + rg) * 4 + 2) * 32;
    int* flg_r1 = flags + ((chain * 16 + rg) * 4 + 3) * 32;

    const unsigned* W16 = (const unsigned*)(wsb + OFF_W16);
    size_t woff;
    if (chain == 0) woff = (role == 0) ? oGW0 : (role == 1) ? oGU0 : (role == 2) ? oGW1 : oGU1;
    else            woff = (role == 0) ? oLW0 : (role == 1) ? oLU0 : (role == 2) ? oLW1 : oLU1;
    const uint4* M4 = (const uint4*)(W16 + woff) + c;

    const int KR  = (role == 0) ? Dd : Hh;
    const int KP2 = KR >> 3;                 // kp per group (12 or 32)
    const int kp0 = grp * KP2, kp1 = kp0 + KP2;

    const int NP  = 4 * GAH;                 // 3072 or 4096
    const int npt = NP >> 10;                // 3 or 4 per thread
    float biasv[4];
    int sgidx[4];
    if (role == 0 || role == 2) {
        const float* bsrc = (chain == 0) ? (role == 0 ? gbi0 : gbi1)
                                         : (role == 0 ? lb0 : lb1);
        #pragma unroll
        for (int i = 0; i < 4; ++i) {
            if (i < npt) {
                const int e = tid + i * 1024;
                const int r = e / GAH, rem = e - r * GAH;
                biasv[i] = bsrc[rem];
                sgidx[i] = r * 1024 + rem;
            } else { biasv[i] = 0; sgidx[i] = 0; }
        }
    }
    const int rA = grp;                      // this thread's batch row
    const int lenA = lengths[rowbase + rA];
    float brz = 0, brr = 0, brh = 0, ow = 0;
    if (chain == 0 && (role == 1 || role == 3)) {
        const float* br = (role == 1) ? gbr0 : gbr1;
        brz = br[c]; brr = br[Hh + c]; brh = br[2 * Hh + c];
    }
    if (role == 3) ow = outW[chain * Hh + c];
    const float outb0 = outb[0];
    float creg = 0.0f;
    float hprev = 0.0f;                      // own h(t-1) f32 (exact masking)

    for (int i = tid; i < 512; i += 1024) sAh[i] = 0;   // h(-1)=0
    __syncthreads();

    for (int t = 0; t < Tt; ++t) {
        // =========== early P-ring probe (r roles): overlap HBM RT with GEMM ===========
        const u64* pslot = nullptr;
        u64 pr[4] = {0, 0, 0, 0};
        if (role == 1 || role == 3) {
            pslot = ((role == 1) ? p0ring : p1ring)
                    + (size_t)(t & (NSP - 1)) * 4096 + rA * GAH + c;
            #pragma unroll
            for (int g = 0; g < 4; ++g)
                if (g < GA) pr[g] = agld(pslot + g * 256);
        }

        // =========== PHASE 1: acquire input (p roles only) ===========
        if (role == 0) {
            if (t >= NSP) {
                if (tid == 0)
                    while (agldi(flg_r0) < t - NSP + 1) __builtin_amdgcn_s_sleep(1);
                __syncthreads();
            }
            if (tid < 4 * Dd) {
                const int r = tid / Dd, k = tid - r * Dd;
                const float v = x[((size_t)(rowbase + r) * Tt + t) * Dd + k];
                sAhh[hidx(k, r)] = __float2half(v);
            }
            __syncthreads();
        } else if (role == 2) {
            const u64* p0 = h0ring + (size_t)(t & (NS0 - 1)) * 1024 + rA * 256 + c;
            const unsigned want = (unsigned)(t + 1);
            u64 v0;
            do { v0 = agld(p0); } while ((unsigned)v0 != want);
            sAhh[hidx(c, rA)] = __float2half(__uint_as_float((unsigned)(v0 >> 32)));
            __syncthreads();
            if (tid == 0)
                __hip_atomic_exchange(flg_p1, t + 1, __ATOMIC_RELEASE,
                                      __HIP_MEMORY_SCOPE_AGENT);
        }
        // r roles: no phase 1 — sAh holds h(t-1) from the previous step.

        // =========== PHASE 2: GEMM; each grp writes its OWN buffer; ONE barrier ===========
        {
            const int b = grp * 4096;
            if (chain == 0) {
                float4 acc[3] = {{0,0,0,0},{0,0,0,0},{0,0,0,0}};
                gemmP<3>(M4, GAH, A4, kp0, kp1, acc);
                #pragma unroll
                for (int g = 0; g < 3; ++g) {
                    sG[b + 0 + g * 256 + c]    = acc[g].x;
                    sG[b + 1024 + g * 256 + c] = acc[g].y;
                    sG[b + 2048 + g * 256 + c] = acc[g].z;
                    sG[b + 3072 + g * 256 + c] = acc[g].w;
                }
            } else {
                float4 acc[4] = {{0,0,0,0},{0,0,0,0},{0,0,0,0},{0,0,0,0}};
                gemmP<4>(M4, GAH, A4, kp0, kp1, acc);
                #pragma unroll
                for (int g = 0; g < 4; ++g) {
                    sG[b + 0 + g * 256 + c]    = acc[g].x;
                    sG[b + 1024 + g * 256 + c] = acc[g].y;
                    sG[b + 2048 + g * 256 + c] = acc[g].z;
                    sG[b + 3072 + g * 256 + c] = acc[g].w;
                }
            }
        }
        __syncthreads();

        // partial-sum combine matching R6 order: (g0+g2) + (g1+g3)
        #define SUM4(i) ((sG[(i)] + sG[8192 + (i)]) + (sG[4096 + (i)] + sG[12288 + (i)]))

        // =========== PHASE 3: publish (p) / poll+update (r) ===========
        if (role == 0 || role == 2) {
            if (role == 2 && t >= NSP) {
                if (tid == 0)
                    while (agldi(flg_r1) < t - NSP + 1) __builtin_amdgcn_s_sleep(1);
                __syncthreads();
            }
            u64* ring = (role == 0) ? p0ring : p1ring;
            u64* slot = ring + (size_t)(t & (NSP - 1)) * 4096;
            for (int i = 0; i < npt; ++i) {
                const float v = SUM4(sgidx[i]) + biasv[i];
                agst(slot + tid + i * 1024,
                     ((u64)__float_as_uint(v) << 32) | (unsigned)(t + 1));
            }
        } else {
            // finish the early probe: spin only if not already arrived
            const unsigned want = (unsigned)(t + 1);
            float P_[4] = {0, 0, 0, 0};
            #pragma unroll
            for (int g = 0; g < 4; ++g) {
                if (g < GA) {
                    u64 v = pr[g];
                    while ((unsigned)v != want) v = agld(pslot + g * 256);
                    P_[g] = __uint_as_float((unsigned)(v >> 32));
                }
            }
            if (role == 1 && t >= NS0) {
                if (tid == 0)
                    while (agldi(flg_p1) < t - NS0 + 1) __builtin_amdgcn_s_sleep(1);
                __syncthreads();
            }
            const int r = rA;
            const float hold = hprev;
            float hn;
            if (chain == 0) {
                const float Qz = SUM4(r * 1024 + c);
                const float Qr = SUM4(r * 1024 + 256 + c);
                const float Qh = SUM4(r * 1024 + 512 + c);
                const float z  = sigf(P_[0] + Qz + brz);
                const float rr = sigf(P_[1] + Qr + brr);
                const float hh = tanhf(P_[2] + rr * (Qh + brh));
                hn = z * hold + (1.0f - z) * hh;
                if (t >= lenA) hn = hold;
            } else {
                const float gi = P_[0] + SUM4(r * 1024 + c);
                const float gf = P_[1] + SUM4(r * 1024 + 256 + c);
                const float gc = P_[2] + SUM4(r * 1024 + 512 + c);
                const float go = P_[3] + SUM4(r * 1024 + 768 + c);
                float cn = sigf(gf) * creg + sigf(gi) * tanhf(gc);
                hn = sigf(go) * tanhf(cn);
                if (t >= lenA) { hn = hold; cn = creg; }
                creg = cn;
            }
            hprev = hn;
            sAhh[hidx(c, r)] = __float2half(hn);     // own h(t) for next GEMM
            if (role == 1) {
                agst(h0ring + (size_t)(t & (NS0 - 1)) * 1024 + r * 256 + c,
                     ((u64)__float_as_uint(hn) << 32) | (unsigned)(t + 1));
            } else {
                float vh = hn * ow;
                for (int o = 32; o > 0; o >>= 1)
                    vh += __shfl_down(vh, o);
                if ((tid & 63) == 0) sRed[tid >> 6] = vh;   // 16 waves
                __syncthreads();
                if (tid < 4) {
                    const float s = sRed[tid * 4] + sRed[tid * 4 + 1]
                                  + sRed[tid * 4 + 2] + sRed[tid * 4 + 3];
                    atomicAdd(&out[(size_t)(rowbase + tid) * Tt + t],
                              s + (chain ? outb0 : 0.0f));
                }
            }
        }
        #undef SUM4
        __syncthreads();   // sAh/sG/sRed safe for next iteration; polls complete
        if (tid == 0 && (role == 1 || role == 3)) {
            __hip_atomic_exchange((role == 1) ? flg_r0 : flg_r1, t + 1,
                                  __ATOMIC_RELEASE, __HIP_MEMORY_SCOPE_AGENT);
        }
    }
}

extern "C" void kernel_launch(void* const* d_in, const int* in_sizes, int n_in,
                              void* d_out, int out_size, void* d_ws, size_t ws_size,
                              hipStream_t stream) {
    const float* x       = (const float*)d_in[0];
    const int*   lengths = (const int*)d_in[1];
    const float* gW0  = (const float*)d_in[2];
    const float* gU0  = (const float*)d_in[3];
    const float* gbi0 = (const float*)d_in[4];
    const float* gbr0 = (const float*)d_in[5];
    const float* gW1  = (const float*)d_in[6];
    const float* gU1  = (const float*)d_in[7];
    const float* gbi1 = (const float*)d_in[8];
    const float* gbr1 = (const float*)d_in[9];
    const float* lW0  = (const float*)d_in[10];
    const float* lU0  = (const float*)d_in[11];
    const float* lb0  = (const float*)d_in[12];
    const float* lW1  = (const float*)d_in[13];
    const float* lU1  = (const float*)d_in[14];
    const float* lb1  = (const float*)d_in[15];
    const float* outW = (const float*)d_in[16];
    const float* outb = (const float*)d_in[17];
    float* out = (float*)d_out;
    char* wsb  = (char*)d_ws;

    hipMemsetAsync(d_ws, 0, OFF_FLG + (16 << 10), stream);
    hipMemsetAsync(d_out, 0, (size_t)out_size * sizeof(float), stream);

    unsigned* W16 = (unsigned*)(wsb + OFF_W16);
    struct { const float* s; size_t o; int K; int ld; } cv[8] = {
        {gW0, oGW0, 96, 768}, {gU0, oGU0, 256, 768},
        {gW1, oGW1, 256, 768}, {gU1, oGU1, 256, 768},
        {lW0, oLW0, 96, 1024}, {lU0, oLU0, 256, 1024},
        {lW1, oLW1, 256, 1024}, {lU1, oLU1, 256, 1024},
    };
    for (int i = 0; i < 8; ++i) {
        const int n = (cv[i].K / 2) * cv[i].ld;
        cvt_pair<<<(n + 255) / 256, 256, 0, stream>>>(cv[i].s, W16 + cv[i].o, n, cv[i].ld);
    }

    (void)hipFuncSetAttribute((const void*)rnn_persist,
                              hipFuncAttributeMaxDynamicSharedMemorySize, SMEM_BYTES);
    rnn_persist<<<dim3(128), dim3(1024), SMEM_BYTES, stream>>>(
        x, lengths, gbi0, gbr0, gbi1, gbr1, lb0, lb1, outW, outb, out, wsb);
}